// Round 1
// baseline (113.009 us; speedup 1.0000x reference)
//
#include <hip/hip_runtime.h>

#define Bn 32
#define Mn 1024
#define Nn 1024

__device__ __forceinline__ void quat_to_R(float qx, float qy, float qz, float qw,
                                          float R[9]) {
    float norm = sqrtf(qx*qx + qy*qy + qz*qz + qw*qw) + 1e-8f;
    float inv = 1.0f / norm;
    float x = qx*inv, y = qy*inv, z = qz*inv, w = qw*inv;
    R[0] = 1.0f - 2.0f*(y*y + z*z);
    R[1] = 2.0f*(x*y - z*w);
    R[2] = 2.0f*(x*z + y*w);
    R[3] = 2.0f*(x*y + z*w);
    R[4] = 1.0f - 2.0f*(x*x + z*z);
    R[5] = 2.0f*(y*z - x*w);
    R[6] = 2.0f*(x*z - y*w);
    R[7] = 2.0f*(y*z + x*w);
    R[8] = 1.0f - 2.0f*(x*x + y*y);
}

// Kernel 1: dis_h + loss accumulation.
// grid = Bn * (Mn/64) = 512 blocks, 256 threads.
// Block handles (b, chunk of 64 m). lane (0..63) = m within chunk; the 4 waves
// (ng=0..3) each cover 256 of the N=1024 model points.
__global__ __launch_bounds__(256) void k1_dis_loss(
    const float* __restrict__ pred_r, const float* __restrict__ pred_t,
    const float* __restrict__ pred_c, const float* __restrict__ target,
    const float* __restrict__ model_points, const float* __restrict__ points,
    const float* __restrict__ wptr, float* __restrict__ loss_accum)
{
    __shared__ __align__(16) float s[Nn * 8];   // [mp.x mp.y mp.z tg.x tg.y tg.z pad pad] -> 32 KB
    __shared__ float red[256];

    const int b    = blockIdx.x >> 4;
    const int mc   = blockIdx.x & 15;
    const int tid  = threadIdx.x;
    const int lane = tid & 63;
    const int ng   = tid >> 6;

    // Stage model_points[b] and target[b] into LDS (coalesced flat reads).
    const float* mp_flat = model_points + b * Nn * 3;
    const float* tg_flat = target      + b * Nn * 3;
    for (int i = tid; i < Nn * 3; i += 256) {
        int n = i / 3;
        int r = i - n * 3;
        s[n * 8 + r]     = mp_flat[i];
        s[n * 8 + 3 + r] = tg_flat[i];
    }

    // Per-lane pose: m = mc*64 + lane
    const int gm = b * Mn + mc * 64 + lane;
    float4 q = *(const float4*)(pred_r + gm * 4);
    float R[9];
    quat_to_R(q.x, q.y, q.z, q.w, R);
    const float tx = points[gm*3+0] + pred_t[gm*3+0];
    const float ty = points[gm*3+1] + pred_t[gm*3+1];
    const float tz = points[gm*3+2] + pred_t[gm*3+2];

    __syncthreads();

    float ssum = 0.0f;
    const int n0 = ng * 256;
    #pragma unroll 4
    for (int n = n0; n < n0 + 256; ++n) {
        const float* row = s + n * 8;
        float4 a  = *(const float4*)(row);      // mp.x mp.y mp.z tg.x
        float2 c2 = *(const float2*)(row + 4);  // tg.y tg.z
        float px = fmaf(a.x, R[0], fmaf(a.y, R[3], fmaf(a.z, R[6], tx)));
        float py = fmaf(a.x, R[1], fmaf(a.y, R[4], fmaf(a.z, R[7], ty)));
        float pz = fmaf(a.x, R[2], fmaf(a.y, R[5], fmaf(a.z, R[8], tz)));
        float dx = px - a.w;
        float dy = py - c2.x;
        float dz = pz - c2.y;
        ssum += sqrtf(fmaf(dx, dx, fmaf(dy, dy, dz * dz)));
    }

    red[tid] = ssum;
    __syncthreads();

    if (ng == 0) {
        float tot = red[lane] + red[lane + 64] + red[lane + 128] + red[lane + 192];
        float dis = tot * (1.0f / (float)Nn);
        float c = fmaxf(pred_c[gm], 1e-6f);
        float w = *wptr;
        float contrib = fmaf(dis, c, -w * logf(c));
        // wave(64) reduce
        for (int off = 32; off > 0; off >>= 1)
            contrib += __shfl_down(contrib, off);
        if (lane == 0)
            atomicAdd(loss_accum, contrib);
    }
}

// Kernel 2: per-b argmax(pred_c), dis_best, new_points, new_target, finalize scalars.
// grid = Bn blocks, 256 threads.
__global__ __launch_bounds__(256) void k2_best(
    const float* __restrict__ pred_r, const float* __restrict__ pred_t,
    const float* __restrict__ pred_c, const float* __restrict__ target,
    const float* __restrict__ model_points, const float* __restrict__ points,
    const float* __restrict__ loss_accum, float* __restrict__ out)
{
    const int b   = blockIdx.x;
    const int tid = threadIdx.x;

    __shared__ float sv[256];
    __shared__ int   si[256];
    __shared__ float Rt[12];
    __shared__ float wred[4];

    // --- argmax over M, first-index tie-break ---
    float bv = -1e30f; int bi = Mn;
    for (int m = tid; m < Mn; m += 256) {
        float v = pred_c[b * Mn + m];
        if (v > bv) { bv = v; bi = m; }
    }
    sv[tid] = bv; si[tid] = bi;
    __syncthreads();
    for (int off = 128; off > 0; off >>= 1) {
        if (tid < off) {
            float v2 = sv[tid + off]; int i2 = si[tid + off];
            if (v2 > sv[tid] || (v2 == sv[tid] && i2 < si[tid])) {
                sv[tid] = v2; si[tid] = i2;
            }
        }
        __syncthreads();
    }

    if (tid == 0) {
        int m = si[0];
        int gm = b * Mn + m;
        float4 q = *(const float4*)(pred_r + gm * 4);
        float R[9];
        quat_to_R(q.x, q.y, q.z, q.w, R);
        #pragma unroll
        for (int i = 0; i < 9; ++i) Rt[i] = R[i];
        Rt[9]  = points[gm*3+0] + pred_t[gm*3+0];
        Rt[10] = points[gm*3+1] + pred_t[gm*3+1];
        Rt[11] = points[gm*3+2] + pred_t[gm*3+2];
    }
    __syncthreads();

    const float R0 = Rt[0], R1 = Rt[1], R2 = Rt[2];
    const float R3 = Rt[3], R4 = Rt[4], R5 = Rt[5];
    const float R6 = Rt[6], R7 = Rt[7], R8 = Rt[8];
    const float tx = Rt[9], ty = Rt[10], tz = Rt[11];

    // --- recompute dis_h[b, best] (1024 pairs over the block) ---
    float ssum = 0.0f;
    for (int n = tid; n < Nn; n += 256) {
        const float* mp = model_points + (b * Nn + n) * 3;
        const float* tg = target      + (b * Nn + n) * 3;
        float px = fmaf(mp[0], R0, fmaf(mp[1], R3, fmaf(mp[2], R6, tx)));
        float py = fmaf(mp[0], R1, fmaf(mp[1], R4, fmaf(mp[2], R7, ty)));
        float pz = fmaf(mp[0], R2, fmaf(mp[1], R5, fmaf(mp[2], R8, tz)));
        float dx = px - tg[0], dy = py - tg[1], dz = pz - tg[2];
        ssum += sqrtf(fmaf(dx, dx, fmaf(dy, dy, dz * dz)));
    }
    for (int off = 32; off > 0; off >>= 1)
        ssum += __shfl_down(ssum, off);
    if ((tid & 63) == 0) wred[tid >> 6] = ssum;
    __syncthreads();
    if (tid == 0) {
        float tot = wred[0] + wred[1] + wred[2] + wred[3];
        atomicAdd(out + 1, tot * (1.0f / (float)Nn) * (1.0f / (float)Bn));
        if (b == 0)
            out[0] = loss_accum[0] * (1.0f / ((float)Bn * (float)Mn));
    }

    // --- new_points / new_target: row-vector transform by R_best ---
    float* np_out = out + 2;
    float* nt_out = out + 2 + Bn * Mn * 3;
    for (int m = tid; m < Mn; m += 256) {
        const float* p = points + (b * Mn + m) * 3;
        float x = p[0] - tx, y = p[1] - ty, z = p[2] - tz;
        float* o = np_out + (b * Mn + m) * 3;
        o[0] = fmaf(x, R0, fmaf(y, R3, z * R6));
        o[1] = fmaf(x, R1, fmaf(y, R4, z * R7));
        o[2] = fmaf(x, R2, fmaf(y, R5, z * R8));
    }
    for (int n = tid; n < Nn; n += 256) {
        const float* p = target + (b * Nn + n) * 3;
        float x = p[0] - tx, y = p[1] - ty, z = p[2] - tz;
        float* o = nt_out + (b * Nn + n) * 3;
        o[0] = fmaf(x, R0, fmaf(y, R3, z * R6));
        o[1] = fmaf(x, R1, fmaf(y, R4, z * R7));
        o[2] = fmaf(x, R2, fmaf(y, R5, z * R8));
    }
}

extern "C" void kernel_launch(void* const* d_in, const int* in_sizes, int n_in,
                              void* d_out, int out_size, void* d_ws, size_t ws_size,
                              hipStream_t stream) {
    const float* pred_r       = (const float*)d_in[0];
    const float* pred_t       = (const float*)d_in[1];
    const float* pred_c       = (const float*)d_in[2];
    const float* target       = (const float*)d_in[3];
    const float* model_points = (const float*)d_in[4];
    // d_in[5] = idx (unused in refine path)
    const float* points       = (const float*)d_in[6];
    const float* wptr         = (const float*)d_in[7];
    // d_in[8] = refine (unused)

    float* out        = (float*)d_out;
    float* loss_accum = (float*)d_ws;

    // zero the atomic accumulators (graph-capture safe)
    hipMemsetAsync(loss_accum, 0, sizeof(float), stream);
    hipMemsetAsync(out, 0, 2 * sizeof(float), stream);

    k1_dis_loss<<<Bn * (Mn / 64), 256, 0, stream>>>(
        pred_r, pred_t, pred_c, target, model_points, points, wptr, loss_accum);
    k2_best<<<Bn, 256, 0, stream>>>(
        pred_r, pred_t, pred_c, target, model_points, points, loss_accum, out);
}

// Round 2
// 98.983 us; speedup vs baseline: 1.1417x; 1.1417x over previous
//
#include <hip/hip_runtime.h>

#define Bn 32
#define Mn 1024
#define Nn 1024

__device__ __forceinline__ float fsqrt(float x) { return __builtin_amdgcn_sqrtf(x); }

__device__ __forceinline__ void quat_to_R(float qx, float qy, float qz, float qw,
                                          float R[9]) {
    float norm = fsqrt(qx*qx + qy*qy + qz*qz + qw*qw) + 1e-8f;
    float inv = 1.0f / norm;
    float x = qx*inv, y = qy*inv, z = qz*inv, w = qw*inv;
    R[0] = 1.0f - 2.0f*(y*y + z*z);
    R[1] = 2.0f*(x*y - z*w);
    R[2] = 2.0f*(x*z + y*w);
    R[3] = 2.0f*(x*y + z*w);
    R[4] = 1.0f - 2.0f*(x*x + z*z);
    R[5] = 2.0f*(y*z - x*w);
    R[6] = 2.0f*(x*z - y*w);
    R[7] = 2.0f*(y*z + x*w);
    R[8] = 1.0f - 2.0f*(x*x + y*y);
}

// Kernel 1: dis_h, per-block loss partial, per-block argmax(pred_c) partial.
// grid = Bn * (Mn/64) = 512 blocks, 256 threads.
// Block = (b, chunk of 64 m); lane = m within chunk; wave ng covers 256 n.
__global__ __launch_bounds__(256) void k1_dis_loss(
    const float* __restrict__ pred_r, const float* __restrict__ pred_t,
    const float* __restrict__ pred_c, const float* __restrict__ target,
    const float* __restrict__ model_points, const float* __restrict__ points,
    const float* __restrict__ wptr,
    float* __restrict__ ws_loss,   // [512] per-block loss partial
    float* __restrict__ ws_amax,   // [512] per-block max conf
    int*   __restrict__ ws_aidx,   // [512] per-block argmax (m index within b)
    float* __restrict__ out)
{
    __shared__ __align__(16) float s[Nn * 8];   // [mp.xyz tg.xyz pad pad] -> 32 KB
    __shared__ float red[256];

    const int b    = blockIdx.x >> 4;
    const int mc   = blockIdx.x & 15;
    const int tid  = threadIdx.x;
    const int lane = tid & 63;
    const int ng   = tid >> 6;

    if (blockIdx.x == 0 && tid == 0) out[1] = 0.0f;  // k2 atomicAdds into out[1]

    // Stage model_points[b] and target[b] into LDS (coalesced flat reads).
    const float* mp_flat = model_points + b * Nn * 3;
    const float* tg_flat = target      + b * Nn * 3;
    for (int i = tid; i < Nn * 3; i += 256) {
        int n = i / 3;
        int r = i - n * 3;
        s[n * 8 + r]     = mp_flat[i];
        s[n * 8 + 3 + r] = tg_flat[i];
    }

    // Per-lane pose: m = mc*64 + lane
    const int gm = b * Mn + mc * 64 + lane;
    float4 q = *(const float4*)(pred_r + gm * 4);
    float R[9];
    quat_to_R(q.x, q.y, q.z, q.w, R);
    const float tx = points[gm*3+0] + pred_t[gm*3+0];
    const float ty = points[gm*3+1] + pred_t[gm*3+1];
    const float tz = points[gm*3+2] + pred_t[gm*3+2];

    __syncthreads();

    float ssum = 0.0f;
    const int n0 = ng * 256;
    #pragma unroll 4
    for (int n = n0; n < n0 + 256; ++n) {
        const float* row = s + n * 8;
        float4 a  = *(const float4*)(row);      // mp.x mp.y mp.z tg.x
        float2 c2 = *(const float2*)(row + 4);  // tg.y tg.z
        float px = fmaf(a.x, R[0], fmaf(a.y, R[3], fmaf(a.z, R[6], tx)));
        float py = fmaf(a.x, R[1], fmaf(a.y, R[4], fmaf(a.z, R[7], ty)));
        float pz = fmaf(a.x, R[2], fmaf(a.y, R[5], fmaf(a.z, R[8], tz)));
        float dx = px - a.w;
        float dy = py - c2.x;
        float dz = pz - c2.y;
        ssum += fsqrt(fmaf(dx, dx, fmaf(dy, dy, dz * dz)));
    }

    red[tid] = ssum;
    __syncthreads();

    if (ng == 0) {
        float tot = red[lane] + red[lane + 64] + red[lane + 128] + red[lane + 192];
        float dis = tot * (1.0f / (float)Nn);
        float c = fmaxf(pred_c[gm], 1e-6f);
        float w = *wptr;
        float contrib = fmaf(dis, c, -w * logf(c));

        // argmax over this block's 64 m (clamped conf; tie -> lowest index)
        float av = c;
        int   ai = mc * 64 + lane;
        #pragma unroll
        for (int off = 32; off > 0; off >>= 1) {
            float ov = __shfl_xor(av, off);
            int   oi = __shfl_xor(ai, off);
            if (ov > av || (ov == av && oi < ai)) { av = ov; ai = oi; }
        }
        // wave(64) sum of loss contrib
        #pragma unroll
        for (int off = 32; off > 0; off >>= 1)
            contrib += __shfl_down(contrib, off);

        if (lane == 0) {
            ws_loss[blockIdx.x] = contrib;
            ws_amax[blockIdx.x] = av;
            ws_aidx[blockIdx.x] = ai;
        }
    }
}

// Kernel 2: finalize. grid = 8*Bn = 256 blocks (8 slices per b), 256 threads.
// Each block: reduce b's 16 argmax partials, build R_best/t_best, transform a
// 128-point slice of points + 128-point slice of target, dis_best slice,
// block 0 sums the 512 loss partials.
__global__ __launch_bounds__(256) void k2_finalize(
    const float* __restrict__ pred_r, const float* __restrict__ pred_t,
    const float* __restrict__ target, const float* __restrict__ model_points,
    const float* __restrict__ points,
    const float* __restrict__ ws_loss, const float* __restrict__ ws_amax,
    const int* __restrict__ ws_aidx,
    float* __restrict__ out)
{
    const int b   = blockIdx.x >> 3;
    const int sl  = blockIdx.x & 7;
    const int tid = threadIdx.x;

    __shared__ float wredA[4];
    __shared__ float wredB[4];

    // --- argmax over b's 16 block-partials (redundant per thread; cached) ---
    float bv = -1.0f; int bi = Mn;
    #pragma unroll
    for (int k = 0; k < 16; ++k) {
        float v = ws_amax[b * 16 + k];
        int   i = ws_aidx[b * 16 + k];
        if (v > bv || (v == bv && i < bi)) { bv = v; bi = i; }
    }
    const int gm = b * Mn + bi;
    float4 q = *(const float4*)(pred_r + gm * 4);
    float R[9];
    quat_to_R(q.x, q.y, q.z, q.w, R);
    const float tx = points[gm*3+0] + pred_t[gm*3+0];
    const float ty = points[gm*3+1] + pred_t[gm*3+1];
    const float tz = points[gm*3+2] + pred_t[gm*3+2];

    // --- transforms: threads 0-127 -> points slice, 128-255 -> target slice ---
    {
        const int t   = tid & 127;
        const int idx = sl * 128 + t;
        const bool is_p = (tid < 128);
        const float* src = is_p ? (points + (b * Mn + idx) * 3)
                                : (target + (b * Nn + idx) * 3);
        float* dst = is_p ? (out + 2 + (b * Mn + idx) * 3)
                          : (out + 2 + Bn * Mn * 3 + (b * Nn + idx) * 3);
        float x = src[0] - tx, y = src[1] - ty, z = src[2] - tz;
        dst[0] = fmaf(x, R[0], fmaf(y, R[3], z * R[6]));
        dst[1] = fmaf(x, R[1], fmaf(y, R[4], z * R[7]));
        dst[2] = fmaf(x, R[2], fmaf(y, R[5], z * R[8]));
    }

    // --- dis_best slice: 128 n on threads 0-127 ---
    float ssum = 0.0f;
    if (tid < 128) {
        const int n = sl * 128 + tid;
        const float* mp = model_points + (b * Nn + n) * 3;
        const float* tg = target      + (b * Nn + n) * 3;
        float px = fmaf(mp[0], R[0], fmaf(mp[1], R[3], fmaf(mp[2], R[6], tx)));
        float py = fmaf(mp[0], R[1], fmaf(mp[1], R[4], fmaf(mp[2], R[7], ty)));
        float pz = fmaf(mp[0], R[2], fmaf(mp[1], R[5], fmaf(mp[2], R[8], tz)));
        float dx = px - tg[0], dy = py - tg[1], dz = pz - tg[2];
        ssum = fsqrt(fmaf(dx, dx, fmaf(dy, dy, dz * dz)));
    }
    #pragma unroll
    for (int off = 32; off > 0; off >>= 1)
        ssum += __shfl_down(ssum, off);
    if ((tid & 63) == 0) wredA[tid >> 6] = ssum;
    __syncthreads();
    if (tid == 0) {
        float tot = wredA[0] + wredA[1] + wredA[2] + wredA[3];
        atomicAdd(out + 1, tot * (1.0f / ((float)Nn * (float)Bn)));
    }

    // --- loss finalize: global block 0 sums the 512 partials ---
    if (blockIdx.x == 0) {
        float ls = ws_loss[tid] + ws_loss[tid + 256];
        #pragma unroll
        for (int off = 32; off > 0; off >>= 1)
            ls += __shfl_down(ls, off);
        if ((tid & 63) == 0) wredB[tid >> 6] = ls;
        __syncthreads();
        if (tid == 0)
            out[0] = (wredB[0] + wredB[1] + wredB[2] + wredB[3])
                     * (1.0f / ((float)Bn * (float)Mn));
    }
}

extern "C" void kernel_launch(void* const* d_in, const int* in_sizes, int n_in,
                              void* d_out, int out_size, void* d_ws, size_t ws_size,
                              hipStream_t stream) {
    const float* pred_r       = (const float*)d_in[0];
    const float* pred_t       = (const float*)d_in[1];
    const float* pred_c       = (const float*)d_in[2];
    const float* target       = (const float*)d_in[3];
    const float* model_points = (const float*)d_in[4];
    // d_in[5] = idx (unused in refine path)
    const float* points       = (const float*)d_in[6];
    const float* wptr         = (const float*)d_in[7];
    // d_in[8] = refine (unused)

    float* out     = (float*)d_out;
    float* ws_loss = (float*)d_ws;            // [512]
    float* ws_amax = ws_loss + 512;           // [512]
    int*   ws_aidx = (int*)(ws_loss + 1024);  // [512]

    k1_dis_loss<<<Bn * (Mn / 64), 256, 0, stream>>>(
        pred_r, pred_t, pred_c, target, model_points, points, wptr,
        ws_loss, ws_amax, ws_aidx, out);
    k2_finalize<<<8 * Bn, 256, 0, stream>>>(
        pred_r, pred_t, target, model_points, points,
        ws_loss, ws_amax, ws_aidx, out);
}

// Round 3
// 92.394 us; speedup vs baseline: 1.2231x; 1.0713x over previous
//
#include <hip/hip_runtime.h>

#define Bn 32
#define Mn 1024
#define Nn 1024

typedef float v2f __attribute__((ext_vector_type(2)));

__device__ __forceinline__ float fsqrt(float x) { return __builtin_amdgcn_sqrtf(x); }
__device__ __forceinline__ v2f fma2(v2f a, v2f b, v2f c) {
    return __builtin_elementwise_fma(a, b, c);
}
__device__ __forceinline__ v2f splat(float x) { v2f v; v.x = x; v.y = x; return v; }

__device__ __forceinline__ void quat_to_R(float qx, float qy, float qz, float qw,
                                          float R[9]) {
    float norm = fsqrt(qx*qx + qy*qy + qz*qz + qw*qw) + 1e-8f;
    float inv = 1.0f / norm;
    float x = qx*inv, y = qy*inv, z = qz*inv, w = qw*inv;
    R[0] = 1.0f - 2.0f*(y*y + z*z);
    R[1] = 2.0f*(x*y - z*w);
    R[2] = 2.0f*(x*z + y*w);
    R[3] = 2.0f*(x*y + z*w);
    R[4] = 1.0f - 2.0f*(x*x + z*z);
    R[5] = 2.0f*(y*z - x*w);
    R[6] = 2.0f*(x*z - y*w);
    R[7] = 2.0f*(y*z + x*w);
    R[8] = 1.0f - 2.0f*(x*x + y*y);
}

// Kernel 1: self-contained per block (b, mc-chunk of 64 m).
// grid = Bn*16 = 512 blocks, 256 threads. Wave ng covers 128 n-pairs.
// Packed-f32 (v_pk_fma_f32) inner loop over pair-interleaved LDS rows.
// Epilogue: loss partial -> ws, per-b argmax (redundant, self-contained),
// dis_best write by owning block, transform slice mc.
__global__ __launch_bounds__(256) void k1_fused(
    const float* __restrict__ pred_r, const float* __restrict__ pred_t,
    const float* __restrict__ pred_c, const float* __restrict__ target,
    const float* __restrict__ model_points, const float* __restrict__ points,
    const float* __restrict__ wptr,
    float* __restrict__ ws_loss,   // [512]
    float* __restrict__ ws_dis,    // [32]
    float* __restrict__ out)
{
    __shared__ __align__(16) float s[(Nn/2) * 12];  // 512 pairs x 12 floats = 24 KB
    __shared__ float red[256];
    __shared__ float sval[256];
    __shared__ int   sidx[256];

    const int b    = blockIdx.x >> 4;
    const int mc   = blockIdx.x & 15;
    const int tid  = threadIdx.x;
    const int lane = tid & 63;
    const int ng   = tid >> 6;

    // Stage into pair-interleaved layout:
    // pair p: [mx0 mx1 my0 my1 mz0 mz1 Tx0 Tx1 Ty0 Ty1 Tz0 Tz1]
    const float* mp_flat = model_points + b * Nn * 3;
    const float* tg_flat = target      + b * Nn * 3;
    for (int i = tid; i < Nn * 3; i += 256) {
        int n = i / 3;
        int r = i - n * 3;
        int p = n >> 1;
        int e = n & 1;
        s[p * 12 + r * 2 + e]     = mp_flat[i];
        s[p * 12 + 6 + r * 2 + e] = tg_flat[i];
    }

    // Per-lane pose: m = mc*64 + lane
    const int gm = b * Mn + mc * 64 + lane;
    float4 q = *(const float4*)(pred_r + gm * 4);
    float R[9];
    quat_to_R(q.x, q.y, q.z, q.w, R);
    const v2f sR0 = splat(R[0]), sR1 = splat(R[1]), sR2 = splat(R[2]);
    const v2f sR3 = splat(R[3]), sR4 = splat(R[4]), sR5 = splat(R[5]);
    const v2f sR6 = splat(R[6]), sR7 = splat(R[7]), sR8 = splat(R[8]);
    const v2f tpx = splat(points[gm*3+0] + pred_t[gm*3+0]);
    const v2f tpy = splat(points[gm*3+1] + pred_t[gm*3+1]);
    const v2f tpz = splat(points[gm*3+2] + pred_t[gm*3+2]);

    __syncthreads();

    v2f acc = splat(0.0f);
    const int p0 = ng * 128;
    #pragma unroll 4
    for (int p = p0; p < p0 + 128; ++p) {
        const float* row = s + p * 12;
        float4 A  = *(const float4*)(row);       // mx0 mx1 my0 my1
        float4 Bq = *(const float4*)(row + 4);   // mz0 mz1 Tx0 Tx1
        float4 Cq = *(const float4*)(row + 8);   // Ty0 Ty1 Tz0 Tz1
        v2f mx; mx.x = A.x;  mx.y = A.y;
        v2f my; my.x = A.z;  my.y = A.w;
        v2f mz; mz.x = Bq.x; mz.y = Bq.y;
        v2f Tx; Tx.x = Bq.z; Tx.y = Bq.w;
        v2f Ty; Ty.x = Cq.x; Ty.y = Cq.y;
        v2f Tz; Tz.x = Cq.z; Tz.y = Cq.w;
        v2f px = fma2(mx, sR0, fma2(my, sR3, fma2(mz, sR6, tpx)));
        v2f py = fma2(mx, sR1, fma2(my, sR4, fma2(mz, sR7, tpy)));
        v2f pz = fma2(mx, sR2, fma2(my, sR5, fma2(mz, sR8, tpz)));
        v2f dx = px - Tx;
        v2f dy = py - Ty;
        v2f dz = pz - Tz;
        v2f d2 = fma2(dx, dx, fma2(dy, dy, dz * dz));
        v2f sr; sr.x = fsqrt(d2.x); sr.y = fsqrt(d2.y);
        acc += sr;
    }

    red[tid] = acc.x + acc.y;
    __syncthreads();

    // wave 0: dis per lane + loss partial
    float dis = 0.0f;
    if (ng == 0) {
        float tot = red[lane] + red[lane + 64] + red[lane + 128] + red[lane + 192];
        dis = tot * (1.0f / (float)Nn);
        float c = fmaxf(pred_c[gm], 1e-6f);
        float w = *wptr;
        float contrib = fmaf(dis, c, -w * logf(c));
        #pragma unroll
        for (int off = 32; off > 0; off >>= 1)
            contrib += __shfl_down(contrib, off);
        if (lane == 0)
            ws_loss[blockIdx.x] = contrib;
    }

    // --- per-b argmax over clamped pred_c (self-contained, first-index ties) ---
    {
        float bv = -1.0f; int bi = 0;
        #pragma unroll
        for (int k = 0; k < 4; ++k) {
            int m = k * 256 + tid;
            float v = fmaxf(pred_c[b * Mn + m], 1e-6f);
            if (v > bv) { bv = v; bi = m; }
        }
        sval[tid] = bv; sidx[tid] = bi;
        __syncthreads();
        for (int off = 128; off > 0; off >>= 1) {
            if (tid < off) {
                float v2 = sval[tid + off]; int i2 = sidx[tid + off];
                if (v2 > sval[tid] || (v2 == sval[tid] && i2 < sidx[tid])) {
                    sval[tid] = v2; sidx[tid] = i2;
                }
            }
            __syncthreads();
        }
    }
    const int best = sidx[0];

    // dis_best: exactly one block per b owns the best m and already has its dis
    if (ng == 0 && (best >> 6) == mc && lane == (best & 63))
        ws_dis[b] = dis;

    // --- transform slice mc: threads 0-63 -> points, 64-127 -> target ---
    if (tid < 128) {
        const int t    = tid & 63;
        const int idx  = mc * 64 + t;
        const bool isp = (tid < 64);
        const int gb = b * Mn + best;
        float4 qb = *(const float4*)(pred_r + gb * 4);
        float Rb[9];
        quat_to_R(qb.x, qb.y, qb.z, qb.w, Rb);
        const float btx = points[gb*3+0] + pred_t[gb*3+0];
        const float bty = points[gb*3+1] + pred_t[gb*3+1];
        const float btz = points[gb*3+2] + pred_t[gb*3+2];
        const float* src = isp ? (points + (b * Mn + idx) * 3)
                               : (target + (b * Nn + idx) * 3);
        float* dst = isp ? (out + 2 + (b * Mn + idx) * 3)
                         : (out + 2 + Bn * Mn * 3 + (b * Nn + idx) * 3);
        float x = src[0] - btx, y = src[1] - bty, z = src[2] - btz;
        dst[0] = fmaf(x, Rb[0], fmaf(y, Rb[3], z * Rb[6]));
        dst[1] = fmaf(x, Rb[1], fmaf(y, Rb[4], z * Rb[7]));
        dst[2] = fmaf(x, Rb[2], fmaf(y, Rb[5], z * Rb[8]));
    }
}

// Kernel 2: tiny finalizer. 1 block, 256 threads. No atomics, no zero-init.
__global__ __launch_bounds__(256) void k2_reduce(
    const float* __restrict__ ws_loss, const float* __restrict__ ws_dis,
    float* __restrict__ out)
{
    const int tid = threadIdx.x;
    __shared__ float wred[4];

    float ls = ws_loss[tid] + ws_loss[tid + 256];
    #pragma unroll
    for (int off = 32; off > 0; off >>= 1)
        ls += __shfl_down(ls, off);
    if ((tid & 63) == 0) wred[tid >> 6] = ls;
    __syncthreads();
    if (tid == 0)
        out[0] = (wred[0] + wred[1] + wred[2] + wred[3])
                 * (1.0f / ((float)Bn * (float)Mn));

    if (tid < 64) {
        float dv = (tid < Bn) ? ws_dis[tid] : 0.0f;
        #pragma unroll
        for (int off = 32; off > 0; off >>= 1)
            dv += __shfl_down(dv, off);
        if (tid == 0)
            out[1] = dv * (1.0f / (float)Bn);
    }
}

extern "C" void kernel_launch(void* const* d_in, const int* in_sizes, int n_in,
                              void* d_out, int out_size, void* d_ws, size_t ws_size,
                              hipStream_t stream) {
    const float* pred_r       = (const float*)d_in[0];
    const float* pred_t       = (const float*)d_in[1];
    const float* pred_c       = (const float*)d_in[2];
    const float* target       = (const float*)d_in[3];
    const float* model_points = (const float*)d_in[4];
    // d_in[5] = idx (unused in refine path)
    const float* points       = (const float*)d_in[6];
    const float* wptr         = (const float*)d_in[7];
    // d_in[8] = refine (unused)

    float* out     = (float*)d_out;
    float* ws_loss = (float*)d_ws;    // [512]
    float* ws_dis  = ws_loss + 512;   // [32]

    k1_fused<<<Bn * (Mn / 64), 256, 0, stream>>>(
        pred_r, pred_t, pred_c, target, model_points, points, wptr,
        ws_loss, ws_dis, out);
    k2_reduce<<<1, 256, 0, stream>>>(ws_loss, ws_dis, out);
}